// Round 9
// baseline (427.044 us; speedup 1.0000x reference)
//
#include <hip/hip_runtime.h>
#include <hip/hip_bf16.h>

#define ENC_DIM 2048
#define DEC_DIM 512
#define ATT_DIM 512
#define BATCH   128
#define NPIX    196
#define NROWS   (BATCH * NPIX)   // 25088

typedef short bf16x8 __attribute__((ext_vector_type(8)));
typedef float f32x4  __attribute__((ext_vector_type(4)));
typedef unsigned short u16x8 __attribute__((ext_vector_type(8)));

__device__ __forceinline__ unsigned short f2bf(float f) {
    union { float f; unsigned u; } v; v.f = f;
    unsigned r = v.u + 0x7fffu + ((v.u >> 16) & 1u);   // RNE
    return (unsigned short)(r >> 16);
}

__device__ __forceinline__ unsigned short bfc(float f) {
    union { __hip_bfloat16 h; unsigned short u; } v;
    v.h = __float2bfloat16(f);                          // RNE, = f2bf
    return v.u;
}

// async global->LDS, 16 B per lane; dst is wave-uniform base + lane*16
__device__ __forceinline__ void gload16(const void* g, void* l) {
    __builtin_amdgcn_global_load_lds(
        (const __attribute__((address_space(1))) unsigned int*)g,
        (__attribute__((address_space(3))) unsigned int*)l, 16, 0, 0);
}

// ---------------------------------------------------------------- prep:
// R8-VERBATIM. 512 blocks x 256 thr, split grid:
//   blocks   0..255 : Wt[a][e] = bf16(W_enc[e][a])  (LDS-tiled transpose)
//   blocks 256..511 : att2'[b][c] = dh[b]@W_dec[:,c] + b_dec[c] + b_enc[c]
//   blocks   0..97  : score[gid] = b_full   (98*256 = 25088 exactly)
__global__ void prep(const float* __restrict__ W_enc, const float* __restrict__ dh,
                     const float* __restrict__ W_dec, const float* __restrict__ b_dec,
                     const float* __restrict__ b_enc, const float* __restrict__ b_full,
                     unsigned short* __restrict__ Wt, float* __restrict__ att2,
                     float* __restrict__ score) {
    __shared__ float ts[64][65];
    const int bid = blockIdx.x, t = threadIdx.x;

    if (bid < 98) score[bid * 256 + t] = b_full[0];

    if (bid < 256) {
        const int a0 = (bid & 7) * 64;
        const int e0 = (bid >> 3) * 64;
        const int tx = t & 15;
        const int ty = t >> 4;
        #pragma unroll
        for (int p = 0; p < 4; ++p) {
            const int e = ty + p * 16;
            const float4 v = *(const float4*)&W_enc[(size_t)(e0 + e) * ATT_DIM + a0 + tx * 4];
            ts[e][tx * 4 + 0] = v.x; ts[e][tx * 4 + 1] = v.y;
            ts[e][tx * 4 + 2] = v.z; ts[e][tx * 4 + 3] = v.w;
        }
        __syncthreads();
        #pragma unroll
        for (int p = 0; p < 4; ++p) {
            const int a = ty + p * 16;
            ushort4 u;
            u.x = f2bf(ts[tx * 4 + 0][a]);
            u.y = f2bf(ts[tx * 4 + 1][a]);
            u.z = f2bf(ts[tx * 4 + 2][a]);
            u.w = f2bf(ts[tx * 4 + 3][a]);
            *(ushort4*)&Wt[(size_t)(a0 + a) * ENC_DIM + e0 + tx * 4] = u;
        }
    } else {
        float* dhs = &ts[0][0];                  // 512-float scratch
        const int kb = bid - 256;
        const int b  = kb >> 1;
        const int c  = (kb & 1) * 256 + t;
        dhs[t]       = dh[b * DEC_DIM + t];
        dhs[t + 256] = dh[b * DEC_DIM + t + 256];
        __syncthreads();
        float acc0 = 0.f, acc1 = 0.f;
        #pragma unroll 8
        for (int d = 0; d < 256; ++d) {
            acc0 += dhs[d]       * W_dec[d * ATT_DIM + c];
            acc1 += dhs[d + 256] * W_dec[(d + 256) * ATT_DIM + c];
        }
        att2[b * ATT_DIM + c] = acc0 + acc1 + b_dec[c] + b_enc[c];
    }
}

// ---------------------------------------------------------------- k2:
// Fused bf16 MFMA GEMM + relu + W_full reduction -> atomic partial scores.
// BM=128, BN=128, BK=64, 4 waves, acc[4][4], XCD-chunked grid swizzle.
// PREFETCH-DISTANCE-1 at 3 blocks/CU (the R4 schedule at the R1 LDS budget):
//   A: bf16 reg-staged SINGLE buffer (18 KB, stride-72, conflict-free; no cvt
//      in MFMA phase).  B: DOUBLE-buffered gload_lds (2x16 KB, XOR involution).
//   Per kstep: issue B(t+1) DMA + A(t+1)->regs FIRST, MFMA(t), bar1 (drain:
//   aL arrived + B(t+1) landed; separates As reads from writes), cvt+ds_write
//   A(t+1), bar2.  Loads get the whole MFMA phase of latency cover.
// LDS = 52736 B -> 3 blocks/CU (3x52736 = 158208 <= 163840).
__launch_bounds__(256, 3)
__global__ void k2_gemm(const float* __restrict__ enc, const unsigned short* __restrict__ Wt,
                        const float* __restrict__ att2, const float* __restrict__ W_full,
                        float* __restrict__ score) {
    __shared__ __align__(16) unsigned short As[128 * 72];      // 18432 B
    __shared__ __align__(16) unsigned short Bs[2][128 * 64];   // 32768 B
    __shared__ float att2s[2][128];
    __shared__ float wfs[128];

    const int t = threadIdx.x;
    const int tile = (blockIdx.x & 7) * 98 + (blockIdx.x >> 3);   // bijective on [0,784)
    const int n0   = (tile & 3) * 128;
    const int row0 = (tile >> 2) * 128;
    const int b0   = row0 / NPIX;
    const int rows_left = (b0 + 1) * NPIX - row0;

    if (t < 128) {
        att2s[0][t] = att2[b0 * ATT_DIM + n0 + t];
        att2s[1][t] = (b0 + 1 < BATCH) ? att2[(b0 + 1) * ATT_DIM + n0 + t] : 0.f;
        wfs[t]      = W_full[n0 + t];
    }

    const int w    = t >> 6;         // wave 0..3
    const int lane = t & 63;
    const int q    = lane >> 4;      // 0..3
    const int cl   = lane & 15;
    const int wm   = (w >> 1) * 64;  // wave's row offset (0/64)
    const int wn   = (w & 1) * 64;   // wave's col offset (0/64)

    f32x4 acc[4][4] = {};

    // A staging: thread t owns rows ar+p*32 (p=0..3), 8 floats at col ak
    const int ar = t >> 3;           // 0..31
    const int ak = (t & 7) * 8;      // 0..56
    const float* encA = enc + (size_t)(row0 + ar) * ENC_DIM + ak;

    // B staging source (swizzled global, linear LDS dest) - verified
    const int br = lane >> 3;                       // 0..7
    const int bc = ((lane & 7) ^ br) * 8;           // swizzled col (shorts)
    const unsigned short* WtB = Wt + (size_t)(n0 + w * 32 + br) * ENC_DIM + bc;

    // ---- prologue: stage kstep 0 (B -> Bs[0] DMA, A -> regs -> cvt -> As)
    {
        #pragma unroll
        for (int i = 0; i < 4; ++i)
            gload16(WtB + (size_t)i * 8 * ENC_DIM, &Bs[0][(w * 32 + i * 8) * 64]);
        #pragma unroll
        for (int p = 0; p < 4; ++p) {
            const float4 v0 = *(const float4*)(encA + (size_t)p * 32 * ENC_DIM);
            const float4 v1 = *(const float4*)(encA + (size_t)p * 32 * ENC_DIM + 4);
            u16x8 u;
            u[0] = bfc(v0.x); u[1] = bfc(v0.y); u[2] = bfc(v0.z); u[3] = bfc(v0.w);
            u[4] = bfc(v1.x); u[5] = bfc(v1.y); u[6] = bfc(v1.z); u[7] = bfc(v1.w);
            *(u16x8*)&As[(ar + p * 32) * 72 + ak] = u;
        }
    }
    __syncthreads();

    // ---- main loop: prefetch distance 1, 2 barriers/kstep
    int cur = 0;
    for (int kk = 0; kk < ENC_DIM; kk += 64, cur ^= 1) {
        const int  nxt = cur ^ 1;
        const bool pf  = (kk + 64 < ENC_DIM);
        float4 aL0, aL1, aL2, aL3, aL4, aL5, aL6, aL7;

        if (pf) {
            // issue next-kstep loads FIRST: full MFMA phase of latency cover
            #pragma unroll
            for (int i = 0; i < 4; ++i)
                gload16(WtB + (size_t)i * 8 * ENC_DIM + kk + 64,
                        &Bs[nxt][(w * 32 + i * 8) * 64]);
            aL0 = *(const float4*)(encA + (size_t)0 * 32 * ENC_DIM + kk + 64);
            aL1 = *(const float4*)(encA + (size_t)0 * 32 * ENC_DIM + kk + 68);
            aL2 = *(const float4*)(encA + (size_t)1 * 32 * ENC_DIM + kk + 64);
            aL3 = *(const float4*)(encA + (size_t)1 * 32 * ENC_DIM + kk + 68);
            aL4 = *(const float4*)(encA + (size_t)2 * 32 * ENC_DIM + kk + 64);
            aL5 = *(const float4*)(encA + (size_t)2 * 32 * ENC_DIM + kk + 68);
            aL6 = *(const float4*)(encA + (size_t)3 * 32 * ENC_DIM + kk + 64);
            aL7 = *(const float4*)(encA + (size_t)3 * 32 * ENC_DIM + kk + 68);
        }

        // MFMA phase: pure bf16 frag reads (no cvt)
        #pragma unroll
        for (int h = 0; h < 2; ++h) {   // two 32-wide K halves
            bf16x8 af[4], bfr[4];
            #pragma unroll
            for (int i = 0; i < 4; ++i)
                af[i]  = *(const bf16x8*)&As[(wm + i * 16 + cl) * 72 + h * 32 + q * 8];
            #pragma unroll
            for (int i = 0; i < 4; ++i)
                bfr[i] = *(const bf16x8*)&Bs[cur][(wn + i * 16 + cl) * 64
                                                  + (((h * 4 + q) ^ (cl & 7)) * 8)];
            #pragma unroll
            for (int mi = 0; mi < 4; ++mi)
                #pragma unroll
                for (int ni = 0; ni < 4; ++ni)
                    acc[mi][ni] = __builtin_amdgcn_mfma_f32_16x16x32_bf16(
                        af[mi], bfr[ni], acc[mi][ni], 0, 0, 0);
        }

        __syncthreads();   // bar1: As frag-reads done; vmcnt drained (aL + B DMA)

        if (pf) {
            u16x8 u0, u1, u2, u3;
            u0[0]=bfc(aL0.x); u0[1]=bfc(aL0.y); u0[2]=bfc(aL0.z); u0[3]=bfc(aL0.w);
            u0[4]=bfc(aL1.x); u0[5]=bfc(aL1.y); u0[6]=bfc(aL1.z); u0[7]=bfc(aL1.w);
            u1[0]=bfc(aL2.x); u1[1]=bfc(aL2.y); u1[2]=bfc(aL2.z); u1[3]=bfc(aL2.w);
            u1[4]=bfc(aL3.x); u1[5]=bfc(aL3.y); u1[6]=bfc(aL3.z); u1[7]=bfc(aL3.w);
            u2[0]=bfc(aL4.x); u2[1]=bfc(aL4.y); u2[2]=bfc(aL4.z); u2[3]=bfc(aL4.w);
            u2[4]=bfc(aL5.x); u2[5]=bfc(aL5.y); u2[6]=bfc(aL5.z); u2[7]=bfc(aL5.w);
            u3[0]=bfc(aL6.x); u3[1]=bfc(aL6.y); u3[2]=bfc(aL6.z); u3[3]=bfc(aL6.w);
            u3[4]=bfc(aL7.x); u3[5]=bfc(aL7.y); u3[6]=bfc(aL7.z); u3[7]=bfc(aL7.w);
            *(u16x8*)&As[(ar +  0) * 72 + ak] = u0;
            *(u16x8*)&As[(ar + 32) * 72 + ak] = u1;
            *(u16x8*)&As[(ar + 64) * 72 + ak] = u2;
            *(u16x8*)&As[(ar + 96) * 72 + ak] = u3;
            __syncthreads();   // bar2: As(t+1) visible
        }
    }

    // ---- epilogue: relu(att1 + att2') * W_full, reduce over block's 128 cols.
    #pragma unroll
    for (int mi = 0; mi < 4; ++mi) {
        float rs[4];
        #pragma unroll
        for (int i = 0; i < 4; ++i) {
            const int lr  = wm + mi * 16 + q * 4 + i;         // local row
            const int sel = (lr >= rows_left) ? 1 : 0;
            float sum = 0.f;
            #pragma unroll
            for (int ni = 0; ni < 4; ++ni) {
                const int j = wn + ni * 16 + cl;              // local col 0..127
                float v = acc[mi][ni][i] + att2s[sel][j];
                v = fmaxf(v, 0.f);
                sum += v * wfs[j];
            }
            rs[i] = sum;
        }
        #pragma unroll
        for (int o = 1; o < 16; o <<= 1) {
            #pragma unroll
            for (int i = 0; i < 4; ++i) rs[i] += __shfl_xor(rs[i], o);
        }
        if (cl == 0) {
            #pragma unroll
            for (int i = 0; i < 4; ++i) {
                const int r = row0 + wm + mi * 16 + q * 4 + i;
                atomicAdd(&score[r], rs[i]);
            }
        }
    }
}

// ---------------------------------------------------------------- k4:
// R8-VERBATIM: fused softmax + awe.  grid (8 e-chunks, 128 b) x 256 thr.
__global__ void k4_awe(const float* __restrict__ enc, const float* __restrict__ score,
                       float* __restrict__ alpha, float* __restrict__ awe) {
    __shared__ float as[NPIX];
    __shared__ float red[4];
    __shared__ f32x4 redv[4][64];
    const int b  = blockIdx.y;
    const int t  = threadIdx.x;
    const int wv = t >> 6, lane = t & 63;
    // --- softmax over P=196 ---
    const float x = (t < NPIX) ? score[b * NPIX + t] : -INFINITY;
    float m = x;
    #pragma unroll
    for (int o = 32; o >= 1; o >>= 1) m = fmaxf(m, __shfl_xor(m, o));
    if (lane == 0) red[wv] = m;
    __syncthreads();
    m = fmaxf(fmaxf(red[0], red[1]), fmaxf(red[2], red[3]));
    const float e = (t < NPIX) ? __expf(x - m) : 0.f;
    float s = e;
    #pragma unroll
    for (int o = 32; o >= 1; o >>= 1) s += __shfl_xor(s, o);
    __syncthreads();
    if (lane == 0) red[wv] = s;
    __syncthreads();
    s = red[0] + red[1] + red[2] + red[3];
    const float a = e / s;
    if (t < NPIX) {
        as[t] = a;
        if (blockIdx.x == 0) alpha[b * NPIX + t] = a;
    }
    __syncthreads();
    // --- awe ---
    const int e0 = blockIdx.x * 256 + lane * 4;
    const float* base = enc + (size_t)b * NPIX * ENC_DIM + e0;
    f32x4 a0 = {}, a1 = {}, a2 = {}, a3 = {};
    int p = wv;
    #pragma unroll 4
    for (int it = 0; it < 12; ++it, p += 16) {
        a0 += as[p]      * *(const f32x4*)(base + (size_t)(p)      * ENC_DIM);
        a1 += as[p + 4]  * *(const f32x4*)(base + (size_t)(p + 4)  * ENC_DIM);
        a2 += as[p + 8]  * *(const f32x4*)(base + (size_t)(p + 8)  * ENC_DIM);
        a3 += as[p + 12] * *(const f32x4*)(base + (size_t)(p + 12) * ENC_DIM);
    }
    a0 += as[p] * *(const f32x4*)(base + (size_t)p * ENC_DIM);   // p = wv + 192 < 196
    redv[wv][lane] = (a0 + a1) + (a2 + a3);
    __syncthreads();
    if (wv == 0) {
        const f32x4 r = (redv[0][lane] + redv[1][lane]) + (redv[2][lane] + redv[3][lane]);
        *(f32x4*)&awe[(size_t)b * ENC_DIM + e0] = r;
    }
}

// ----------------------------------------------------------------
extern "C" void kernel_launch(void* const* d_in, const int* in_sizes, int n_in,
                              void* d_out, int out_size, void* d_ws, size_t ws_size,
                              hipStream_t stream) {
    const float* enc    = (const float*)d_in[0];   // [128,196,2048]
    const float* dh     = (const float*)d_in[1];   // [128,512]
    const float* W_enc  = (const float*)d_in[2];   // [2048,512]
    const float* b_enc  = (const float*)d_in[3];   // [512]
    const float* W_dec  = (const float*)d_in[4];   // [512,512]
    const float* b_dec  = (const float*)d_in[5];   // [512]
    const float* W_full = (const float*)d_in[6];   // [512]
    const float* b_full = (const float*)d_in[7];   // scalar

    float* awe   = (float*)d_out;                  // [128,2048]
    float* alpha = awe + BATCH * ENC_DIM;          // [128,196] final output

    // workspace: Wt bf16 (2 MB) + att2 (256 KB) + score (100 KB)
    unsigned short* Wt    = (unsigned short*)d_ws;
    float*          att2  = (float*)((char*)d_ws + (size_t)ATT_DIM * ENC_DIM * 2);
    float*          score = att2 + (size_t)BATCH * ATT_DIM;

    prep   <<<512,          256, 0, stream>>>(W_enc, dh, W_dec, b_dec, b_enc, b_full,
                                              Wt, att2, score);
    k2_gemm<<<784,          256, 0, stream>>>(enc, Wt, att2, W_full, score);
    k4_awe <<<dim3(8, 128), 256, 0, stream>>>(enc, score, alpha, awe);
}